// Round 4
// baseline (880.899 us; speedup 1.0000x reference)
//
#include <hip/hip_runtime.h>
#include <math.h>

// Problem constants (from reference): B=8, C=32, F=32, K=3, H=W=32
#define NB 8
#define NC 32
#define NF 32
#define NH 32
#define NW 32
#define NQ 9
#define CSPLIT 4            // channel-loop split factor (8 channels per block)
#define CPB (NC / CSPLIT)   // channels per block
#define TROWS 18            // staged padded rows per half-image (16 + 2 halo)
#define TS 34               // padded tile row stride (W+2)
#define TILE_N (TROWS * TS) // 612
#define CROWS (NQ * CPB)    // 72 coefficient rows per block
#define CROW_F 16           // floats per padded coeff row (a0..a5,_,_,d0..d3,_x4)

typedef float f2 __attribute__((ext_vector_type(2)));
__device__ __forceinline__ f2 sp(float v) { return (f2){v, v}; }

// Block = 256 threads, each owns 2 vertically-adjacent output pixels
// (16 rows x 32 cols = half image). Grid = B*F*2 halves * CSPLIT = 2048
// -> 8 blocks/CU -> 32 waves/CU. Channel partials combined with HW fp32
// atomics (out pre-zeroed).
//
// v4 = v1 structure (rolling x-prefetch + double-buffered LDS tile, one
// barrier per channel) with ONE change: the block's 72 coefficient rows
// are staged into LDS once at block start (4.6 KB, covered by the
// already-existing first barrier). Inner-loop coeff access becomes
// 2x ds_read_b128 + 1x ds_read_b64 at immediate offsets, same-address
// broadcast across the wave (bank-conflict-free). Rationale from v1/v3
// evidence:
//  - v1 s_load path: 8 blocks/CU x 2.88 KB distinct-f coeff sets thrash
//    the scalar L1 (~16 KB) -> persistent L2-latency s_loads, prefetch
//    depth capped by the SGPR file; plus packed ops pairing two SGPR
//    splats violate the 1-SGPR-per-VALU rule -> ~10 v_mov/iteration.
//  - v3 per-lane VMEM path: 288 flat loads/thread + 64-bit addr arith
//    flooded the VALU (VALUBusy 30%, kernel 70 us). Dead end.
//  - LDS broadcast: results land in VGPRs (packed ops legal, no movs),
//    zero per-iteration address math, deep lgkmcnt pipelining.
__global__ __launch_bounds__(256, 8) void ka_conv_rational_kernel(
    const float* __restrict__ x,     // [B, C, H, W]
    const float* __restrict__ nums,  // [F*Q*C, 6]
    const float* __restrict__ dens,  // [F*Q*C, 4]
    float* __restrict__ out)         // [B, F, H, W]
{
    __shared__ float tile[2][TILE_N];        // 4896 B
    __shared__ float cf[CROWS * CROW_F];     // 4608 B

    const int t    = threadIdx.x;
    const int bid  = blockIdx.x;          // 0..2047
    const int cs   = bid & (CSPLIT - 1);  // channel chunk
    const int half = (bid >> 2) & 1;      // which 16-row half of the image
    const int bf   = bid >> 3;            // = b*NF + f, 0..255
    const int f    = bf & (NF - 1);
    const int bb   = bf >> 5;             // / NF
    const int xx   = t & 31;              // output column
    const int ty   = t >> 5;              // 0..7 -> owns rows 2*ty, 2*ty+1
    const int c0   = cs * CPB;

    // c-invariant staging geometry: element idx of the 18x34 padded tile.
    int  soff[3];
    bool svalid[3];
#pragma unroll
    for (int i = 0; i < 3; ++i) {
        int idx = t + i * 256;
        int ry  = idx / TS;
        int rx  = idx - ry * TS;
        int gy  = half * 16 + ry - 1;
        int gx  = rx - 1;
        bool ok = (idx < TILE_N) && (gy >= 0) && (gy < NH) && (gx >= 0) && (gx < NW);
        svalid[i] = ok;
        soff[i]   = ok ? (gy * NW + gx) : 0; // clamped: always in-bounds
    }

    const float* __restrict__ xb = x + ((size_t)bb * NC + c0) * NH * NW;

    // ---- one-time coefficient staging into LDS (covered by the first
    // per-channel barrier below; no extra __syncthreads needed) ----
    // rows (q, ci): threads 0..71 stage nums (24 B), 128..199 stage dens.
    if (t < CROWS) {
        const int q = t >> 3, ci = t & (CPB - 1);
        const size_t r = ((size_t)(f * NQ + q)) * NC + (c0 + ci);
        const float* ap = nums + r * 6;      // 24 B, 8-B aligned
        f2 a01 = *(const f2*)ap;
        f2 a23 = *(const f2*)(ap + 2);
        f2 a45 = *(const f2*)(ap + 4);
        float* dst = cf + t * CROW_F;
        *(f2*)(dst)     = a01;
        *(f2*)(dst + 2) = a23;
        *(f2*)(dst + 4) = a45;
    } else if (t >= 128 && t < 128 + CROWS) {
        const int i = t - 128;
        const int q = i >> 3, ci = i & (CPB - 1);
        const size_t r = ((size_t)(f * NQ + q)) * NC + (c0 + ci);
        float4 dd = *(const float4*)(dens + r * 4); // 16 B aligned
        *(float4*)(cf + i * CROW_F + 8) = dd;
    }

    // prefetch first channel into registers
    float st[3];
#pragma unroll
    for (int i = 0; i < 3; ++i)
        st[i] = xb[soff[i]];

    f2 acc = {0.f, 0.f};

    for (int ci = 0; ci < CPB; ++ci) {
        float* tl = tile[ci & 1];

        // write staged channel (zero-padded) to LDS
#pragma unroll
        for (int i = 0; i < 3; ++i) {
            int idx = t + i * 256;
            if (idx < TILE_N)
                tl[idx] = svalid[i] ? st[i] : 0.f;
        }
        // prefetch next channel (latency hidden behind compute below)
        if (ci + 1 < CPB) {
            const float* xc = xb + (size_t)(ci + 1) * NH * NW;
#pragma unroll
            for (int i = 0; i < 3; ++i)
                st[i] = xc[soff[i]];
        }
        __syncthreads(); // double-buffered: buffer (ci&1) next rewritten at ci+2

        // 4x3 neighborhood covering both pixels' 3x3 windows
        float n[4][3];
#pragma unroll
        for (int dy = 0; dy < 4; ++dy)
#pragma unroll
            for (int dx = 0; dx < 3; ++dx)
                n[dy][dx] = tl[(ty * 2 + dy) * TS + (xx + dx)];

#pragma unroll
        for (int q = 0; q < NQ; ++q) {
            // coeff row from LDS: broadcast ds_read_b128 x2 + ds_read_b64,
            // base = ci*64 B, immediate offset q*512 B (+0/+16/+32).
            const float* cp = cf + (q * CPB + ci) * CROW_F;
            float4 A03 = *(const float4*)cp;        // a0 a1 a2 a3
            f2     A45 = *(const f2*)(cp + 4);      // a4 a5
            float4 DD  = *(const float4*)(cp + 8);  // d0 d1 d2 d3
            const int qi = q / 3, qj = q - qi * 3;

            // both pixels' terms evaluated as <2 x float> (v_pk_* ops)
            f2 w = {n[qi][qj], n[qi + 1][qj]};
            f2 nu = __builtin_elementwise_fma(sp(A45.y), w, sp(A45.x));
            nu = __builtin_elementwise_fma(nu, w, sp(A03.w));
            nu = __builtin_elementwise_fma(nu, w, sp(A03.z));
            nu = __builtin_elementwise_fma(nu, w, sp(A03.y));
            nu = __builtin_elementwise_fma(nu, w, sp(A03.x));
            f2 dp = __builtin_elementwise_fma(sp(DD.w), w, sp(DD.z));
            dp = __builtin_elementwise_fma(dp, w, sp(DD.y));
            dp = __builtin_elementwise_fma(dp, w, sp(DD.x));
            dp = dp * w;
            f2 de = 1.0f + __builtin_elementwise_abs(dp);
            f2 r  = {__builtin_amdgcn_rcpf(de.x), __builtin_amdgcn_rcpf(de.y)};
            acc = __builtin_elementwise_fma(nu, r, acc);
        }
    }

    const int y0 = half * 16 + ty * 2;
    float* op = out + ((size_t)bf * NH + y0) * NW + xx;
    unsafeAtomicAdd(op, acc.x);
    unsafeAtomicAdd(op + NW, acc.y);
}

extern "C" void kernel_launch(void* const* d_in, const int* in_sizes, int n_in,
                              void* d_out, int out_size, void* d_ws, size_t ws_size,
                              hipStream_t stream) {
    const float* x    = (const float*)d_in[0];
    const float* nums = (const float*)d_in[1];
    const float* dens = (const float*)d_in[2];
    float* out = (float*)d_out;

    // atomic accumulation target must start at zero (harness poisons d_out)
    hipMemsetAsync(d_out, 0, (size_t)out_size * sizeof(float), stream);

    dim3 grid(NB * NF * 2 * CSPLIT); // 2048 blocks: (b, f, half, csplit)
    dim3 block(256);
    ka_conv_rational_kernel<<<grid, block, 0, stream>>>(x, nums, dens, out);
}

// Round 5
// 79.772 us; speedup vs baseline: 11.0428x; 11.0428x over previous
//
#include <hip/hip_runtime.h>
#include <math.h>

// Problem constants (from reference): B=8, C=32, F=32, K=3, H=W=32
#define NB 8
#define NC 32
#define NF 32
#define NH 32
#define NW 32
#define NQ 9
#define CSPLIT 8            // channel-loop split factor (4 channels per block)
#define CPB (NC / CSPLIT)   // channels per block = 4
#define TROWS 34            // full padded image rows (32 + 2 halo)
#define TS 34               // padded tile row stride (W+2)
#define TILE_N (TROWS * TS) // 1156

typedef float f2 __attribute__((ext_vector_type(2)));
__device__ __forceinline__ f2 sp(float v) { return (f2){v, v}; }

// v5 = v1 skeleton (s_load coefficient feed — proven best of {s_load,
// VMEM(v3: 70us addr flood), LDS(v4: spill storm, 3 GB scratch traffic)};
// rolling x-prefetch; double-buffered LDS tile; per-channel barrier) with
// the WORK PER COEFFICIENT ROW doubled:
//   each thread owns 4 vertically-adjacent output pixels (full 32x32
//   image per block), CSPLIT 4->8 keeps grid at 2048 = 8 blocks/CU.
// Rationale: v1 kernel ~34us vs ~14us VALU floor; the stall is per-(q,c)
// overhead (s_load latency under shared lgkmcnt + barrier cadence), paid
// per coefficient row while FMA work is paid per pixel. 4 px/row halves
// the overhead-to-work ratio at identical occupancy/LDS/grid shape.
// Channel partials combined with HW fp32 atomics (out pre-zeroed).
__global__ __launch_bounds__(256, 8) void ka_conv_rational_kernel(
    const float* __restrict__ x,     // [B, C, H, W]
    const float* __restrict__ nums,  // [F*Q*C, 6]
    const float* __restrict__ dens,  // [F*Q*C, 4]
    float* __restrict__ out)         // [B, F, H, W]
{
    __shared__ float tile[2][TILE_N]; // 2 * 1156 * 4 = 9248 B

    const int t   = threadIdx.x;
    const int bid = blockIdx.x;          // 0..2047
    const int cs  = bid & (CSPLIT - 1);  // channel chunk
    const int bf  = bid >> 3;            // = b*NF + f, 0..255
    const int f   = bf & (NF - 1);
    const int bb  = bf >> 5;             // / NF
    const int xx  = t & 31;              // output column
    const int ty  = t >> 5;              // 0..7 -> owns rows 4*ty .. 4*ty+3
    const int c0  = cs * CPB;

    // c-invariant staging geometry: element idx of the 34x34 padded tile.
    // 1156 elements / 256 threads -> 5 staging slots (last is partial).
    int  soff[5];
    bool svalid[5];
#pragma unroll
    for (int i = 0; i < 5; ++i) {
        int idx = t + i * 256;
        int ry  = idx / TS;
        int rx  = idx - ry * TS;
        int gy  = ry - 1;
        int gx  = rx - 1;
        bool ok = (idx < TILE_N) && (gy >= 0) && (gy < NH) && (gx >= 0) && (gx < NW);
        svalid[i] = ok;
        soff[i]   = ok ? (gy * NW + gx) : 0; // clamped: always in-bounds
    }

    const float* __restrict__ xb    = x    + ((size_t)bb * NC + c0) * NH * NW;
    const float* __restrict__ abase = nums + (size_t)f * NQ * NC * 6;
    const float* __restrict__ bbase = dens + (size_t)f * NQ * NC * 4;

    // prefetch first channel into registers
    float st[5];
#pragma unroll
    for (int i = 0; i < 5; ++i)
        st[i] = xb[soff[i]];

    f2 acc01 = {0.f, 0.f};
    f2 acc23 = {0.f, 0.f};

    for (int ci = 0; ci < CPB; ++ci) {
        const int c = c0 + ci;
        float* tl = tile[ci & 1];

        // write staged channel (zero-padded) to LDS
#pragma unroll
        for (int i = 0; i < 5; ++i) {
            int idx = t + i * 256;
            if (idx < TILE_N) // i<4: always true (constant-folds); i=4: t<132
                tl[idx] = svalid[i] ? st[i] : 0.f;
        }
        // prefetch next channel (latency hidden behind compute below)
        if (ci + 1 < CPB) {
            const float* xc = xb + (size_t)(ci + 1) * NH * NW;
#pragma unroll
            for (int i = 0; i < 5; ++i)
                st[i] = xc[soff[i]];
        }
        __syncthreads(); // double-buffered: buffer (ci&1) next rewritten at ci+2

        // 6x3 neighborhood covering all 4 pixels' 3x3 windows
        float n[6][3];
#pragma unroll
        for (int dy = 0; dy < 6; ++dy)
#pragma unroll
            for (int dx = 0; dx < 3; ++dx)
                n[dy][dx] = tl[(ty * 4 + dy) * TS + (xx + dx)];

#pragma unroll
        for (int q = 0; q < NQ; ++q) {
            // block-uniform coefficient loads -> scalar (s_load) path
            const float* ap = abase + (size_t)(q * NC + c) * 6;
            const float* bp = bbase + (size_t)(q * NC + c) * 4;
            const float a0 = ap[0], a1 = ap[1], a2 = ap[2],
                        a3 = ap[3], a4 = ap[4], a5 = ap[5];
            const float d0 = bp[0], d1 = bp[1], d2 = bp[2], d3 = bp[3];
            const int qi = q / 3, qj = q - qi * 3;

            // 4 pixels' terms as two <2 x float> streams (v_pk_* ops);
            // two independent chains also improve latency hiding.
            f2 w01 = {n[qi][qj],     n[qi + 1][qj]};
            f2 w23 = {n[qi + 2][qj], n[qi + 3][qj]};

            f2 nu01 = __builtin_elementwise_fma(sp(a5), w01, sp(a4));
            f2 nu23 = __builtin_elementwise_fma(sp(a5), w23, sp(a4));
            nu01 = __builtin_elementwise_fma(nu01, w01, sp(a3));
            nu23 = __builtin_elementwise_fma(nu23, w23, sp(a3));
            nu01 = __builtin_elementwise_fma(nu01, w01, sp(a2));
            nu23 = __builtin_elementwise_fma(nu23, w23, sp(a2));
            nu01 = __builtin_elementwise_fma(nu01, w01, sp(a1));
            nu23 = __builtin_elementwise_fma(nu23, w23, sp(a1));
            nu01 = __builtin_elementwise_fma(nu01, w01, sp(a0));
            nu23 = __builtin_elementwise_fma(nu23, w23, sp(a0));

            f2 dp01 = __builtin_elementwise_fma(sp(d3), w01, sp(d2));
            f2 dp23 = __builtin_elementwise_fma(sp(d3), w23, sp(d2));
            dp01 = __builtin_elementwise_fma(dp01, w01, sp(d1));
            dp23 = __builtin_elementwise_fma(dp23, w23, sp(d1));
            dp01 = __builtin_elementwise_fma(dp01, w01, sp(d0));
            dp23 = __builtin_elementwise_fma(dp23, w23, sp(d0));
            dp01 = dp01 * w01;
            dp23 = dp23 * w23;

            f2 de01 = 1.0f + __builtin_elementwise_abs(dp01);
            f2 de23 = 1.0f + __builtin_elementwise_abs(dp23);
            f2 r01 = {__builtin_amdgcn_rcpf(de01.x), __builtin_amdgcn_rcpf(de01.y)};
            f2 r23 = {__builtin_amdgcn_rcpf(de23.x), __builtin_amdgcn_rcpf(de23.y)};
            acc01 = __builtin_elementwise_fma(nu01, r01, acc01);
            acc23 = __builtin_elementwise_fma(nu23, r23, acc23);
        }
    }

    const int y0 = ty * 4;
    float* op = out + ((size_t)bf * NH + y0) * NW + xx;
    unsafeAtomicAdd(op,          acc01.x);
    unsafeAtomicAdd(op + NW,     acc01.y);
    unsafeAtomicAdd(op + 2 * NW, acc23.x);
    unsafeAtomicAdd(op + 3 * NW, acc23.y);
}

extern "C" void kernel_launch(void* const* d_in, const int* in_sizes, int n_in,
                              void* d_out, int out_size, void* d_ws, size_t ws_size,
                              hipStream_t stream) {
    const float* x    = (const float*)d_in[0];
    const float* nums = (const float*)d_in[1];
    const float* dens = (const float*)d_in[2];
    float* out = (float*)d_out;

    // atomic accumulation target must start at zero (harness poisons d_out)
    hipMemsetAsync(d_out, 0, (size_t)out_size * sizeof(float), stream);

    dim3 grid(NB * NF * CSPLIT); // 2048 blocks: (b, f, csplit) -> 8/CU
    dim3 block(256);
    ka_conv_rational_kernel<<<grid, block, 0, stream>>>(x, nums, dens, out);
}